// Round 10
// baseline (219.968 us; speedup 1.0000x reference)
//
#include <hip/hip_runtime.h>
#include <stdint.h>

#define HW   50176
#define IMW  224
#define NS   4096
#define EPSF 1e-6f
#define NRB  16384   // ratio hist buckets/frame (top 14 bits of float pattern)
#define NKB  2048    // key hist buckets/frame (top 11 of 21 key bits)

// Workspace float layout (max index 180480 -> 721,920 B, proven):
// CTRL  [0..255]: [0] pose_loss [1] depth_abs_sum [3] normal_sum
//   [4..7] pg_sum[f] [8..11] gp_sum[f] [12..15] selwsum[f]
//   [16..19] maskcnt[f] [20..23] scale[f]
//   ints I=(int*)(W+24): I[0..3] selcnt I[4..7] nn I[8..11] mc I[12..15] candcnt
//     I[16..19] kcandcnt I[20..23] b1 I[24..27] r1 I[28..31] b2 I[32..35] r2
//     I[36..39] bk I[40..43] rk
//   [72..119] relgt[f][12]
//   [125] hist-done ticket  [126] cham-done ticket
// [256..65791]     HIST (uint 4*16384)   -> overlay post-scan: PS (float4 4*4096)
// [65792..73983]   KHIST (uint 4*2048)   -> overlay post-scan: SEL[0..8191]
// [73984..82175]   SEL[8192..16383]
// [82176..147711]  GS (float4 4*4096)
// [147712..180479] CAND(4*4096)+KCAND(4*4096) -> overlay in k_finish: RMIN (2*4*4096)
#define OFF_PS   256
#define OFF_HIST 256
#define OFF_KH   65792
#define OFF_SEL  65792
#define OFF_GS   82176
#define OFF_RMIN 147712

__device__ __forceinline__ bool finitef(float x){
  return (__float_as_uint(x) & 0x7f800000u) != 0x7f800000u;
}
__device__ __forceinline__ uint32_t ordenc(float f){
  uint32_t u = __float_as_uint(f);
  return (u & 0x80000000u) ? ~u : (u | 0x80000000u);
}
__device__ __forceinline__ float orddec(uint32_t e){
  uint32_t u = (e & 0x80000000u) ? (e & 0x7fffffffu) : ~e;
  return __uint_as_float(u);
}
__device__ __forceinline__ int wsum_i(int v){
  #pragma unroll
  for (int o=32;o;o>>=1) v += __shfl_down(v,o);
  return v;
}
__device__ __forceinline__ float wsum_f(float v){
  #pragma unroll
  for (int o=32;o;o>>=1) v += __shfl_down(v,o);
  return v;
}
__device__ __forceinline__ int block_prefix_incl(int v, int* lds){
  int tid = threadIdx.x;
  lds[tid] = v; __syncthreads();
  #pragma unroll
  for (int off=1; off<256; off<<=1){
    int add = (tid>=off) ? lds[tid-off] : 0;
    __syncthreads();
    lds[tid] += add;
    __syncthreads();
  }
  return lds[tid];
}
__device__ __forceinline__ int block_prefix_incl_1024(int v, int* lds){
  int tid = threadIdx.x;
  lds[tid] = v; __syncthreads();
  #pragma unroll
  for (int off=1; off<1024; off<<=1){
    int add = (tid>=off) ? lds[tid-off] : 0;
    __syncthreads();
    lds[tid] += add;
    __syncthreads();
  }
  return lds[tid];
}

__device__ void inv4(const float* A, float* out){
  float M[4][8];
  for (int i=0;i<4;i++) for (int j=0;j<4;j++){ M[i][j]=A[i*4+j]; M[i][4+j]=(i==j)?1.f:0.f; }
  for (int c=0;c<4;c++){
    int piv=c; float mx=fabsf(M[c][c]);
    for (int r=c+1;r<4;r++){ float a=fabsf(M[r][c]); if (a>mx){ mx=a; piv=r; } }
    if (piv!=c) for (int j=0;j<8;j++){ float t=M[c][j]; M[c][j]=M[piv][j]; M[piv][j]=t; }
    float inv = 1.f/M[c][c];
    for (int j=0;j<8;j++) M[c][j]*=inv;
    for (int r=0;r<4;r++){
      if (r==c) continue;
      float fv = M[r][c];
      for (int j=0;j<8;j++) M[r][j] -= fv*M[c][j];
    }
  }
  for (int i=0;i<4;i++) for (int j=0;j<4;j++) out[i*4+j]=M[i][4+j];
}
__device__ void mat4(const float* A, const float* B, float* C){
  for (int i=0;i<4;i++) for (int j=0;j<4;j++){
    float s=0.f;
    for (int k=0;k<4;k++) s += A[i*4+k]*B[k*4+j];
    C[i*4+j]=s;
  }
}
__device__ __forceinline__ float3 normal_at(const float* D, float sc, int x, int y,
                                            float cx, float cy, float fx, float fy){
  int base = y*IMW + x;
  float dL = D[base-1]*sc,   dR = D[base+1]*sc;
  float dU = D[base-IMW]*sc, dD = D[base+IMW]*sc;
  float xl = ((float)(x-1)-cx)/fx, xr = ((float)(x+1)-cx)/fx, xc = ((float)x-cx)/fx;
  float yu = ((float)(y-1)-cy)/fy, yd = ((float)(y+1)-cy)/fy, yc = ((float)y-cy)/fy;
  float ax = xc*dD - xc*dU, ay = yd*dD - yu*dU, az = dD - dU;
  float bx = xr*dR - xl*dL, by = yc*dR - yc*dL, bz = dR - dL;
  float nx = ay*bz - az*by;
  float ny = az*bx - ax*bz;
  float nz = ax*by - ay*bx;
  float l = sqrtf(nx*nx + ny*ny + nz*nz);
  float inv = 1.f/fmaxf(l, EPSF);
  return make_float3(nx*inv, ny*inv, nz*inv);
}

// ---- 0: zero CTRL+HIST+KHIST (float4 stores; 73984 dwords = 18496 float4) ----
__global__ __launch_bounds__(256) void k_zero(float* W){
  int gid = blockIdx.x*256 + threadIdx.x;   // 73*256 = 18688 >= 18496
  if (gid < 18496) ((float4*)W)[gid] = make_float4(0.f,0.f,0.f,0.f);
}

// ---- 1: LDS histograms (32 blocks) + pose (block 32) + scan in last-block tail ----
__global__ __launch_bounds__(1024) void k_hist(const float* dp_, const float* dg_,
                                               const float* pp, const float* pg, float* W){
  const int bid = blockIdx.x, tid = threadIdx.x;
  __shared__ uint32_t lh[NRB + NKB];        // 72 KB
  int* I = (int*)(W + 24);
  if (bid == 32){
    if (tid == 0){
      float i0p[16], i0g[16];
      inv4(pp, i0p); inv4(pg, i0g);
      float s = 0.f;
      for (int f=0; f<4; f++){
        float rp[16], rg[16];
        mat4(i0p, pp+16*f, rp);
        mat4(i0g, pg+16*f, rg);
        for (int k=0;k<16;k++) s += fabsf(rp[k]-rg[k]);
        for (int i=0;i<3;i++) for (int j=0;j<3;j++) W[72+f*12+i*3+j] = rg[i*4+j];
        for (int i=0;i<3;i++) W[72+f*12+9+i] = rg[i*4+3];
      }
      W[0] = s/64.f;
    }
  } else {
    for (int j=tid; j<NRB+NKB; j+=1024) lh[j] = 0u;
    __syncthreads();
    const int f = bid >> 3;
    const int base = (bid & 7) * 6272;        // 8 blocks/frame * 6272 px
    int nn_l = 0, mc_l = 0;
    #pragma unroll
    for (int it=0; it<2; ++it){
      int t = tid + it*1024;
      if (t < 1568){                          // 1568 float4 per block
        float4 d4 = *(const float4*)(dg_ + f*HW + base + t*4);
        float4 p4 = *(const float4*)(dp_ + f*HW + base + t*4);
        float dv[4] = {d4.x,d4.y,d4.z,d4.w};
        float pv[4] = {p4.x,p4.y,p4.z,p4.w};
        #pragma unroll
        for (int k=0;k<4;++k){
          int r = base + t*4 + k;
          bool mg = (dv[k] > EPSF) && finitef(dv[k]);
          bool m  = mg && finitef(pv[k]) && (pv[k] > EPSF);
          mc_l += mg ? 1 : 0;
          nn_l += m ? 1 : 0;
          if (m){
            uint32_t u = __float_as_uint(pv[k] / fmaxf(dv[k], EPSF));
            atomicAdd(&lh[u>>18], 1u);
          }
          uint32_t key = ((uint32_t)(mg?1:0) << 20) | (((uint32_t)r*2654435761u) & 0xFFFFFu);
          atomicAdd(&lh[NRB + (key>>10)], 1u);
        }
      }
    }
    __syncthreads();
    uint32_t* HIST  = (uint32_t*)(W + OFF_HIST) + f*NRB;
    uint32_t* KHIST = (uint32_t*)(W + OFF_KH)   + f*NKB;
    for (int j=tid; j<NRB; j+=1024){ uint32_t v = lh[j]; if (v) atomicAdd(&HIST[j], v); }
    for (int j=tid; j<NKB; j+=1024){ uint32_t v = lh[NRB+j]; if (v) atomicAdd(&KHIST[j], v); }
    int nw = wsum_i(nn_l), mw = wsum_i(mc_l);
    if ((tid & 63) == 0){ atomicAdd(&I[4+f], nw); atomicAdd(&I[8+f], mw); }
  }
  // ---- last-block-closes-the-door: ticket; winner (33rd) runs the scan ----
  __syncthreads();
  __shared__ int win;
  if (tid == 0){
    __threadfence();
    win = (atomicAdd((int*)(W+125), 1) == 32) ? 1 : 0;
  }
  __syncthreads();
  if (!win) return;
  __threadfence();
  int* pls = (int*)lh;     // reuse LDS for the 1024-wide prefix
  for (int f=0; f<4; ++f){
    const uint32_t* FH = (const uint32_t*)(W + OFF_HIST) + f*NRB;
    int loc[16], part = 0;
    #pragma unroll
    for (int j=0;j<16;j++){ loc[j] = (int)FH[tid*16+j]; part += loc[j]; }
    int incl = block_prefix_incl_1024(part, pls);
    int nn = I[4+f];
    if (nn > 0){
      int k1 = (nn-1)>>1, k2 = nn>>1;
      int acc = incl - part;
      #pragma unroll
      for (int j=0;j<16;j++){
        int c = loc[j];
        if (k1 >= acc && k1 < acc+c){ I[20+f] = tid*16+j; I[24+f] = k1-acc; }
        if (k2 >= acc && k2 < acc+c){ I[28+f] = tid*16+j; I[32+f] = k2-acc; }
        acc += c;
      }
    } else if (tid == 0){ I[20+f] = -1; I[28+f] = -1; }
    __syncthreads();
    const uint32_t* FK = (const uint32_t*)(W + OFF_KH) + f*NKB;
    int l0 = (int)FK[tid*2], l1 = (int)FK[tid*2+1];
    int kincl = block_prefix_incl_1024(l0+l1, pls);
    {
      const int tt = HW - NS;
      int acc = kincl - (l0+l1);
      if (tt >= acc && tt < acc+l0){ I[36+f] = tid*2;   I[40+f] = tt-acc; }
      acc += l0;
      if (tt >= acc && tt < acc+l1){ I[36+f] = tid*2+1; I[40+f] = tt-acc; }
    }
    __syncthreads();
  }
}

// ---- 3: collect candidates + bulk top-k (196 blocks, block-aggregated atomics) ----
__global__ __launch_bounds__(256) void k_collect(const float* dp_, const float* dg_, float* W){
  __shared__ int slds[256];
  __shared__ int base_s, base_c;
  const int bid = blockIdx.x, tid = threadIdx.x;
  const int f = bid / 49;
  const int base = (bid - f*49)*1024;
  int* I = (int*)(W + 24);
  uint32_t* CAND  = (uint32_t*)(W + OFF_RMIN);
  uint32_t* KCAND = CAND + 16384;
  int* SEL = (int*)(W + OFF_SEL);
  const int b1 = I[20+f], b2 = I[28+f], bk = I[36+f];
  float4 d4 = *(const float4*)(dg_ + f*HW + base + tid*4);
  float4 p4 = *(const float4*)(dp_ + f*HW + base + tid*4);
  float dv[4] = {d4.x,d4.y,d4.z,d4.w};
  float pv[4] = {p4.x,p4.y,p4.z,p4.w};
  bool sf[4], cf[4];
  uint32_t cu[4];
  int cnt_s = 0, cnt_c = 0;
  #pragma unroll
  for (int k=0;k<4;++k){
    int r = base + tid*4 + k;
    bool mg = (dv[k] > EPSF) && finitef(dv[k]);
    bool m  = mg && finitef(pv[k]) && (pv[k] > EPSF);
    cu[k] = 0u; cf[k] = false;
    if (m){
      cu[k] = __float_as_uint(pv[k] / fmaxf(dv[k], EPSF));
      int bu = (int)(cu[k]>>18);
      cf[k] = (bu == b1 || bu == b2);
    }
    uint32_t key = ((uint32_t)(mg?1:0) << 20) | (((uint32_t)r*2654435761u) & 0xFFFFFu);
    int kb = (int)(key>>10);
    sf[k] = kb > bk;
    cnt_s += sf[k] ? 1 : 0;
    cnt_c += cf[k] ? 1 : 0;
    if (kb == bk){
      int p = atomicAdd(&I[16+f], 1);
      if (p < 4096) KCAND[f*4096 + p] = (uint32_t)r;
    }
  }
  int packed = (cnt_c<<11) | cnt_s;
  int incl = block_prefix_incl(packed, slds);
  int excl = incl - packed;
  int excl_s = excl & 0x7FF, excl_c = excl >> 11;
  int tot = slds[255];
  if (tid == 0){
    base_s = atomicAdd(&I[0+f],  tot & 0x7FF);
    base_c = atomicAdd(&I[12+f], tot >> 11);
  }
  __syncthreads();
  int ps = base_s + excl_s, pc = base_c + excl_c;
  #pragma unroll
  for (int k=0;k<4;++k){
    int r = base + tid*4 + k;
    if (sf[k]) SEL[(f<<12) + ps++] = r;
    if (cf[k]){ if (pc < 4096) CAND[f*4096 + pc] = cu[k]; pc++; }
  }
}

// exact value at 0-based rank r among {c in sC[0..nc): (c>>18)==b},
// via 3-level LDS histogram refinement (bits [17:10], [9:2], [1:0]).
__device__ uint32_t refine_rank(const uint32_t* sC, int nc, uint32_t b, int r,
                                int* hist, int* slds){
  const int tid = threadIdx.x;
  __shared__ int ssb, srem;
  hist[tid] = 0; __syncthreads();
  for (int t=tid; t<nc; t+=256){
    uint32_t c = sC[t];
    if ((c>>18) == b) atomicAdd(&hist[(c>>10)&0xFF], 1);
  }
  __syncthreads();
  int part = hist[tid];
  int incl = block_prefix_incl(part, slds);
  if (part > 0 && r >= incl-part && r < incl){ ssb = tid; srem = r-(incl-part); }
  __syncthreads();
  uint32_t pfx = (b<<8) | (uint32_t)ssb;
  int r2 = srem;
  __syncthreads();
  hist[tid] = 0; __syncthreads();
  for (int t=tid; t<nc; t+=256){
    uint32_t c = sC[t];
    if ((c>>10) == pfx) atomicAdd(&hist[(c>>2)&0xFF], 1);
  }
  __syncthreads();
  part = hist[tid];
  incl = block_prefix_incl(part, slds);
  if (part > 0 && r2 >= incl-part && r2 < incl){ ssb = tid; srem = r2-(incl-part); }
  __syncthreads();
  uint32_t pfx2 = (pfx<<8) | (uint32_t)ssb;
  int r3 = srem;
  __syncthreads();
  if (tid < 4) hist[tid] = 0;
  __syncthreads();
  for (int t=tid; t<nc; t+=256){
    uint32_t c = sC[t];
    if ((c>>2) == pfx2) atomicAdd(&hist[c&3], 1);
  }
  __syncthreads();
  int h0=hist[0], h1=hist[1], h2=hist[2];
  uint32_t lo = (r3 < h0) ? 0u : (r3 < h0+h1) ? 1u : (r3 < h0+h1+h2) ? 2u : 3u;
  __syncthreads();
  return (pfx2<<2) | lo;
}

// ---- 4: exact median + key-threshold completion, RMIN init, gather (4 blocks) ----
__global__ __launch_bounds__(256) void k_finish(const float* dg_, const float* pts_,
                                                const float* intr, float* W){
  const int f = blockIdx.x, tid = threadIdx.x;
  __shared__ __align__(16) uint32_t smem[8192];   // sC 16KB + sK 16KB
  __shared__ int hist[256];
  __shared__ int slds[256];
  int* I = (int*)(W + 24);
  uint32_t* CAND  = (uint32_t*)(W + OFF_RMIN);
  uint32_t* KCAND = CAND + 16384;
  int* SEL = (int*)(W + OFF_SEL);
  uint32_t* sC = smem;
  uint32_t* sK = smem + 4096;
  int nc = min(I[12+f], 4096), nk = min(I[16+f], 4096);
  for (int t=tid; t<nc; t+=256) sC[t] = CAND[f*4096 + t];
  for (int t=tid; t<nk; t+=256) sK[t] = KCAND[f*4096 + t];
  __syncthreads();
  for (int t=tid; t<4096; t+=256){
    CAND [f*4096 + t] = 0xFF800000u;   // RMIN dir0 slice f = ordenc(+inf)
    KCAND[f*4096 + t] = 0xFF800000u;   // RMIN dir1 slice f
  }
  int nn = I[4+f], mc = I[8+f];
  float scale = 1.f;
  if (nn > 0){
    uint32_t v1 = refine_rank(sC, nc, (uint32_t)I[20+f], I[24+f], hist, slds);
    uint32_t v2 = refine_rank(sC, nc, (uint32_t)I[28+f], I[32+f], hist, slds);
    float med = 0.5f*(__uint_as_float(v1) + __uint_as_float(v2));
    scale = (nn < 16 || !finitef(med)) ? 1.f : fminf(fmaxf(med, 1e-3f), 1e3f);
  }
  {
    int bk = I[36+f], rk = I[40+f];
    uint32_t maskbit = ((uint32_t)bk >> 10) & 1u;
    for (int t=tid; t<nk; t+=256){
      uint32_t i = sK[t];
      uint32_t key = (maskbit<<20) | ((i*2654435761u) & 0xFFFFFu);
      int rank = 0;
      for (int j=0;j<nk;j++){
        uint32_t key2 = (maskbit<<20) | ((sK[j]*2654435761u) & 0xFFFFFu);
        rank += (key2 < key);
      }
      if (rank >= rk){ int p = atomicAdd(&I[0+f], 1); SEL[(f<<12)+p] = (int)i; }
    }
  }
  __syncthreads();
  if (tid == 0){ W[20+f] = scale; W[16+f] = (float)mc; }
  float fx = fmaxf(intr[f*9+0], EPSF), fy = fmaxf(intr[f*9+4], EPSF);
  float cx = intr[f*9+2], cy = intr[f*9+5];
  const float* R = W + 72 + f*12;
  float wl = 0.f;
  for (int t=tid; t<4096; t+=256){
    int idx = SEL[(f<<12)+t];
    float dgv = dg_[f*HW + idx];
    bool mg = (dgv > EPSF) && finitef(dgv);
    float wv = mg ? 1.f : 0.f;
    wl += wv;
    const float* p = pts_ + (size_t)(f*HW + idx)*3;
    ((float4*)(W + OFF_PS))[(f<<12)+t] = make_float4(p[0], p[1], p[2], wv);
    float d = dgv * scale;
    int y = idx / IMW, x = idx - y*IMW;
    float X = ((float)x - cx)/fx * d;
    float Y = ((float)y - cy)/fy * d;
    float4 gs;
    gs.x = R[0]*X + R[1]*Y + R[2]*d + R[9];
    gs.y = R[3]*X + R[4]*Y + R[5]*d + R[10];
    gs.z = R[6]*X + R[7]*Y + R[8]*d + R[11];
    gs.w = wv;
    ((float4*)(W + OFF_GS))[(f<<12)+t] = gs;
  }
  float ws = wsum_f(wl);
  if ((tid & 63) == 0) atomicAdd(&W[12+f], ws);
}

// ---- 5: chamfer row-min + fused normals/depth + final combine in last-block tail ----
__global__ __launch_bounds__(256) void k_cham(const float* dp_, const float* dg_,
                                              const float* intr, float* W, float* out){
  __shared__ __align__(16) float4 tile[256];   // 4 KB
  __shared__ float rsum[8];
  const int bid = blockIdx.x, tid = threadIdx.x;
  const float4* PS = (const float4*)(W + OFF_PS);
  const float4* GS = (const float4*)(W + OFF_GS);
  {
    int dir = bid >> 8;
    int rem = bid & 255;
    int f = rem >> 6;
    int t64 = rem & 63;
    int rc = t64 & 3;        // 4 row-chunks of 1024
    int gc = t64 >> 2;       // 16 gt-chunks of 256
    const float4* A = dir ? GS : PS;
    const float4* B = dir ? PS : GS;
    uint32_t* RM = (uint32_t*)(W + OFF_RMIN) + dir*16384 + (f<<12);
    {
      float4 b = B[(f<<12) + (gc<<8) + tid];
      float gg = fmaf(b.x,b.x, fmaf(b.y,b.y, b.z*b.z));
      bool v = b.w > 0.f;
      tile[tid] = make_float4(v?b.x:0.f, v?b.y:0.f, v?b.z:0.f, v ? -0.5f*gg : -INFINITY);
    }
    __syncthreads();
    int r0 = (rc<<10) + tid;   // rows r0, r0+256, r0+512, r0+768
    float4 a0 = A[(f<<12)+r0];
    float4 a1 = A[(f<<12)+r0+256];
    float4 a2 = A[(f<<12)+r0+512];
    float4 a3 = A[(f<<12)+r0+768];
    float rh0 = -0.5f*fmaf(a0.x,a0.x,fmaf(a0.y,a0.y,a0.z*a0.z));
    float rh1 = -0.5f*fmaf(a1.x,a1.x,fmaf(a1.y,a1.y,a1.z*a1.z));
    float rh2 = -0.5f*fmaf(a2.x,a2.x,fmaf(a2.y,a2.y,a2.z*a2.z));
    float rh3 = -0.5f*fmaf(a3.x,a3.x,fmaf(a3.y,a3.y,a3.z*a3.z));
    float m0 = -INFINITY, m1 = -INFINITY, m2 = -INFINITY, m3 = -INFINITY;
    #pragma unroll 8
    for (int j=0;j<256;++j){
      float4 g = tile[j];
      float d0 = fmaf(a0.z,g.z, fmaf(a0.y,g.y, fmaf(a0.x,g.x, rh0)));
      float d1 = fmaf(a1.z,g.z, fmaf(a1.y,g.y, fmaf(a1.x,g.x, rh1)));
      float d2 = fmaf(a2.z,g.z, fmaf(a2.y,g.y, fmaf(a2.x,g.x, rh2)));
      float d3 = fmaf(a3.z,g.z, fmaf(a3.y,g.y, fmaf(a3.x,g.x, rh3)));
      m0 = fmaxf(m0, d0 + g.w);
      m1 = fmaxf(m1, d1 + g.w);
      m2 = fmaxf(m2, d2 + g.w);
      m3 = fmaxf(m3, d3 + g.w);
    }
    atomicMin(&RM[r0    ], ordenc(-2.f*m0));
    atomicMin(&RM[r0+256], ordenc(-2.f*m1));
    atomicMin(&RM[r0+512], ordenc(-2.f*m2));
    atomicMin(&RM[r0+768], ordenc(-2.f*m3));
  }
  // fused normals + depth L1 (512 blocks * 392 px = 200704)
  {
    int f = bid >> 7;
    int base = (bid & 127) * 392;
    float sc = W[20+f];
    float fx = fmaxf(intr[f*9+0], EPSF), fy = fmaxf(intr[f*9+4], EPSF);
    float cx = intr[f*9+2], cy = intr[f*9+5];
    float dl = 0.f, nl = 0.f;
    #pragma unroll
    for (int it=0; it<2; ++it){
      int t = tid + it*256;
      if (t < 392){
        int r = base + t;
        int y = r / IMW, x = r - y*IMW;
        float dgv = dg_[f*HW+r], dpv = dp_[f*HW+r];
        bool mg = (dgv > EPSF) && finitef(dgv);
        float mv = mg ? 1.f : 0.f;
        dl += fabsf(dpv - dgv*sc) * mv;
        if (x > 0 && x < IMW-1 && y > 0 && y < IMW-1){
          float3 n1 = normal_at(dp_ + f*HW, 1.f, x, y, cx, cy, fx, fy);
          float3 n2 = normal_at(dg_ + f*HW, sc,  x, y, cx, cy, fx, fy);
          float l1 = sqrtf(n1.x*n1.x + n1.y*n1.y + n1.z*n1.z);
          float l2 = sqrtf(n2.x*n2.x + n2.y*n2.y + n2.z*n2.z);
          float i1 = 1.f/fmaxf(l1, EPSF), i2 = 1.f/fmaxf(l2, EPSF);
          float cosv = (n1.x*n2.x + n1.y*n2.y + n1.z*n2.z)*i1*i2;
          cosv = fminf(fmaxf(cosv, -1.f), 1.f);
          nl += (1.f - cosv) * mv;
        } else {
          nl += mv;   // border: both normals zero -> cos=0
        }
      }
    }
    float ds = wsum_f(dl), ns2 = wsum_f(nl);
    if ((tid & 63) == 0){ rsum[tid>>6] = ds; rsum[4+(tid>>6)] = ns2; }
    __syncthreads();
    if (tid == 0){
      atomicAdd(&W[1], rsum[0]+rsum[1]+rsum[2]+rsum[3]);
      atomicAdd(&W[3], rsum[4]+rsum[5]+rsum[6]+rsum[7]);
    }
  }
  // ---- last-block-closes-the-door: winner (512th) runs chamfin + final combine ----
  __syncthreads();
  __shared__ int win;
  if (tid == 0){
    __threadfence();
    win = (atomicAdd((int*)(W+126), 1) == 511) ? 1 : 0;
  }
  __syncthreads();
  if (!win) return;
  __threadfence();
  {
    const uint32_t* RM = (const uint32_t*)(W + OFF_RMIN);
    float sums[8];
    #pragma unroll
    for (int grp=0; grp<8; ++grp){
      int dir = grp >> 2, f = grp & 3;
      const float4* A = dir ? GS : PS;
      float local = 0.f;
      for (int row=tid; row<4096; row+=256){
        float val = orddec(RM[dir*16384 + (f<<12) + row]);
        float d = isinf(val) ? 1e9f : sqrtf(fmaxf(val, 1e-12f));
        local += d * A[(f<<12)+row].w;
      }
      local = wsum_f(local);
      __syncthreads();
      if ((tid & 63) == 0) rsum[tid>>6] = local;
      __syncthreads();
      float s = 0.f;
      if (tid == 0){ for (int k=0;k<4;k++) s += rsum[k]; }
      sums[grp] = s;    // valid on thread 0
      __syncthreads();
    }
    if (tid == 0){
      float md = fmaxf(W[16]+W[17]+W[18]+W[19], 1.f);
      float depth_loss  = W[1]/md;
      float normal_loss = W[3]/md;
      float cds = 0.f, oks = 0.f;
      for (int f=0; f<4; f++){
        if (W[16+f] >= 10.f){
          float denom = fmaxf(W[12+f], 1.f);
          cds += sums[f]/denom + sums[4+f]/denom;
          oks += 1.f;
        }
      }
      float points_loss = cds / fmaxf(oks, 1.f);
      out[0] = W[0] + depth_loss + points_loss + normal_loss;
    }
  }
}

extern "C" void kernel_launch(void* const* d_in, const int* in_sizes, int n_in,
                              void* d_out, int out_size, void* d_ws, size_t ws_size,
                              hipStream_t stream){
  const float* depth_pred  = (const float*)d_in[0];
  const float* points_pred = (const float*)d_in[1];
  const float* depth_gt    = (const float*)d_in[2];
  const float* intr        = (const float*)d_in[3];
  const float* pose_pred   = (const float*)d_in[4];
  const float* pose_gt     = (const float*)d_in[5];
  float* out = (float*)d_out;
  float* W   = (float*)d_ws;

  k_zero   <<<73,  256,  0, stream>>>(W);
  k_hist   <<<33,  1024, 0, stream>>>(depth_pred, depth_gt, pose_pred, pose_gt, W);
  k_collect<<<196, 256,  0, stream>>>(depth_pred, depth_gt, W);
  k_finish <<<4,   256,  0, stream>>>(depth_gt, points_pred, intr, W);
  k_cham   <<<512, 256,  0, stream>>>(depth_pred, depth_gt, intr, W, out);
}

// Round 11
// 175.617 us; speedup vs baseline: 1.2525x; 1.2525x over previous
//
#include <hip/hip_runtime.h>
#include <stdint.h>

#define HW   50176
#define IMW  224
#define NS   4096
#define EPSF 1e-6f
#define NRB  16384   // ratio hist buckets/frame (top 14 bits of float pattern)
#define NKB  2048    // key hist buckets/frame (top 11 of 21 key bits)

// Workspace float layout (max index 180480 -> 721,920 B, proven):
// CTRL  [0..255]: [0] pose_loss [1] depth_abs_sum [3] normal_sum
//   [4..7] pg_sum[f] [8..11] gp_sum[f] [12..15] selwsum[f]
//   [16..19] maskcnt[f] [20..23] scale[f]
//   ints I=(int*)(W+24): I[0..3] selcnt I[4..7] nn I[8..11] mc I[12..15] candcnt
//     I[16..19] kcandcnt I[20..23] b1 I[24..27] r1 I[28..31] b2 I[32..35] r2
//     I[36..39] bk I[40..43] rk
//   [72..119] relgt[f][12]
// [256..65791]     HIST (uint 4*16384)   -> overlay post-scan: PS (float4 4*4096)
// [65792..73983]   KHIST (uint 4*2048)   -> overlay post-scan: SEL[0..8191]
// [73984..82175]   SEL[8192..16383]
// [82176..147711]  GS (float4 4*4096)
// [147712..180479] CAND(4*4096)+KCAND(4*4096) -> overlay in k_finish: RMIN (2*4*4096)
// NOTE (R10 lesson): no __threadfence / cross-block tickets anywhere — device-scope
// fences cost ~60+ us aggregated at 512 blocks on MI355X; dispatch boundaries are cheaper.
#define OFF_PS   256
#define OFF_HIST 256
#define OFF_KH   65792
#define OFF_SEL  65792
#define OFF_GS   82176
#define OFF_RMIN 147712

__device__ __forceinline__ bool finitef(float x){
  return (__float_as_uint(x) & 0x7f800000u) != 0x7f800000u;
}
__device__ __forceinline__ uint32_t ordenc(float f){
  uint32_t u = __float_as_uint(f);
  return (u & 0x80000000u) ? ~u : (u | 0x80000000u);
}
__device__ __forceinline__ float orddec(uint32_t e){
  uint32_t u = (e & 0x80000000u) ? (e & 0x7fffffffu) : ~e;
  return __uint_as_float(u);
}
__device__ __forceinline__ int wsum_i(int v){
  #pragma unroll
  for (int o=32;o;o>>=1) v += __shfl_down(v,o);
  return v;
}
__device__ __forceinline__ float wsum_f(float v){
  #pragma unroll
  for (int o=32;o;o>>=1) v += __shfl_down(v,o);
  return v;
}
__device__ __forceinline__ int block_prefix_incl(int v, int* lds){
  int tid = threadIdx.x;
  lds[tid] = v; __syncthreads();
  #pragma unroll
  for (int off=1; off<256; off<<=1){
    int add = (tid>=off) ? lds[tid-off] : 0;
    __syncthreads();
    lds[tid] += add;
    __syncthreads();
  }
  return lds[tid];
}

__device__ void inv4(const float* A, float* out){
  float M[4][8];
  for (int i=0;i<4;i++) for (int j=0;j<4;j++){ M[i][j]=A[i*4+j]; M[i][4+j]=(i==j)?1.f:0.f; }
  for (int c=0;c<4;c++){
    int piv=c; float mx=fabsf(M[c][c]);
    for (int r=c+1;r<4;r++){ float a=fabsf(M[r][c]); if (a>mx){ mx=a; piv=r; } }
    if (piv!=c) for (int j=0;j<8;j++){ float t=M[c][j]; M[c][j]=M[piv][j]; M[piv][j]=t; }
    float inv = 1.f/M[c][c];
    for (int j=0;j<8;j++) M[c][j]*=inv;
    for (int r=0;r<4;r++){
      if (r==c) continue;
      float fv = M[r][c];
      for (int j=0;j<8;j++) M[r][j] -= fv*M[c][j];
    }
  }
  for (int i=0;i<4;i++) for (int j=0;j<4;j++) out[i*4+j]=M[i][4+j];
}
__device__ void mat4(const float* A, const float* B, float* C){
  for (int i=0;i<4;i++) for (int j=0;j<4;j++){
    float s=0.f;
    for (int k=0;k<4;k++) s += A[i*4+k]*B[k*4+j];
    C[i*4+j]=s;
  }
}
__device__ __forceinline__ float3 normal_at(const float* D, float sc, int x, int y,
                                            float cx, float cy, float fx, float fy){
  int base = y*IMW + x;
  float dL = D[base-1]*sc,   dR = D[base+1]*sc;
  float dU = D[base-IMW]*sc, dD = D[base+IMW]*sc;
  float xl = ((float)(x-1)-cx)/fx, xr = ((float)(x+1)-cx)/fx, xc = ((float)x-cx)/fx;
  float yu = ((float)(y-1)-cy)/fy, yd = ((float)(y+1)-cy)/fy, yc = ((float)y-cy)/fy;
  float ax = xc*dD - xc*dU, ay = yd*dD - yu*dU, az = dD - dU;
  float bx = xr*dR - xl*dL, by = yc*dR - yc*dL, bz = dR - dL;
  float nx = ay*bz - az*by;
  float ny = az*bx - ax*bz;
  float nz = ax*by - ay*bx;
  float l = sqrtf(nx*nx + ny*ny + nz*nz);
  float inv = 1.f/fmaxf(l, EPSF);
  return make_float3(nx*inv, ny*inv, nz*inv);
}

// ---- 0: zero CTRL+HIST+KHIST (float4 stores; 73984 dwords = 18496 float4) ----
__global__ __launch_bounds__(256) void k_zero(float* W){
  int gid = blockIdx.x*256 + threadIdx.x;   // 73*256 = 18688 >= 18496
  if (gid < 18496) ((float4*)W)[gid] = make_float4(0.f,0.f,0.f,0.f);
}

// ---- 1: LDS-aggregated histograms (32 blocks) + pose (block 32) ----
__global__ __launch_bounds__(1024) void k_hist(const float* dp_, const float* dg_,
                                               const float* pp, const float* pg, float* W){
  const int bid = blockIdx.x, tid = threadIdx.x;
  if (bid == 32){
    if (tid != 0) return;
    float i0p[16], i0g[16];
    inv4(pp, i0p); inv4(pg, i0g);
    float s = 0.f;
    for (int f=0; f<4; f++){
      float rp[16], rg[16];
      mat4(i0p, pp+16*f, rp);
      mat4(i0g, pg+16*f, rg);
      for (int k=0;k<16;k++) s += fabsf(rp[k]-rg[k]);
      for (int i=0;i<3;i++) for (int j=0;j<3;j++) W[72+f*12+i*3+j] = rg[i*4+j];
      for (int i=0;i<3;i++) W[72+f*12+9+i] = rg[i*4+3];
    }
    W[0] = s/64.f;
    return;
  }
  __shared__ uint32_t lh[NRB + NKB];        // 72 KB
  for (int j=tid; j<NRB+NKB; j+=1024) lh[j] = 0u;
  __syncthreads();
  const int f = bid >> 3;
  const int base = (bid & 7) * 6272;        // 8 blocks/frame * 6272 px
  int nn_l = 0, mc_l = 0;
  #pragma unroll
  for (int it=0; it<2; ++it){
    int t = tid + it*1024;
    if (t < 1568){                          // 1568 float4 per block
      float4 d4 = *(const float4*)(dg_ + f*HW + base + t*4);
      float4 p4 = *(const float4*)(dp_ + f*HW + base + t*4);
      float dv[4] = {d4.x,d4.y,d4.z,d4.w};
      float pv[4] = {p4.x,p4.y,p4.z,p4.w};
      #pragma unroll
      for (int k=0;k<4;++k){
        int r = base + t*4 + k;
        bool mg = (dv[k] > EPSF) && finitef(dv[k]);
        bool m  = mg && finitef(pv[k]) && (pv[k] > EPSF);
        mc_l += mg ? 1 : 0;
        nn_l += m ? 1 : 0;
        if (m){
          uint32_t u = __float_as_uint(pv[k] / fmaxf(dv[k], EPSF));
          atomicAdd(&lh[u>>18], 1u);
        }
        uint32_t key = ((uint32_t)(mg?1:0) << 20) | (((uint32_t)r*2654435761u) & 0xFFFFFu);
        atomicAdd(&lh[NRB + (key>>10)], 1u);
      }
    }
  }
  __syncthreads();
  uint32_t* HIST  = (uint32_t*)(W + OFF_HIST) + f*NRB;
  uint32_t* KHIST = (uint32_t*)(W + OFF_KH)   + f*NKB;
  for (int j=tid; j<NRB; j+=1024){ uint32_t v = lh[j]; if (v) atomicAdd(&HIST[j], v); }
  for (int j=tid; j<NKB; j+=1024){ uint32_t v = lh[NRB+j]; if (v) atomicAdd(&KHIST[j], v); }
  int* I = (int*)(W + 24);
  int nw = wsum_i(nn_l), mw = wsum_i(mc_l);
  if ((tid & 63) == 0){ atomicAdd(&I[4+f], nw); atomicAdd(&I[8+f], mw); }
}

// ---- 2: prefix over histograms -> bucket+rank (4 blocks) ----
__global__ __launch_bounds__(256) void k_scan(float* W){
  const int f = blockIdx.x, tid = threadIdx.x;
  __shared__ int slds[256];
  int* I = (int*)(W + 24);
  const uint32_t* FH = (const uint32_t*)(W + OFF_HIST) + f*NRB;
  int part = 0;
  for (int j=0;j<64;j++) part += (int)FH[tid*64+j];
  int incl = block_prefix_incl(part, slds);
  int nn = I[4+f];
  if (nn > 0){
    int k1 = (nn-1)>>1, k2 = nn>>1;
    int acc = incl - part;
    for (int j=0;j<64;j++){
      int c = (int)FH[tid*64+j];
      if (k1 >= acc && k1 < acc+c){ I[20+f] = tid*64+j; I[24+f] = k1-acc; }
      if (k2 >= acc && k2 < acc+c){ I[28+f] = tid*64+j; I[32+f] = k2-acc; }
      acc += c;
    }
  } else if (tid == 0){ I[20+f] = -1; I[28+f] = -1; }
  __syncthreads();
  const uint32_t* FK = (const uint32_t*)(W + OFF_KH) + f*NKB;
  int kpart = 0;
  int kl[8];
  #pragma unroll
  for (int j=0;j<8;j++){ kl[j] = (int)FK[tid*8+j]; kpart += kl[j]; }
  int kincl = block_prefix_incl(kpart, slds);
  {
    const int tt = HW - NS;
    int acc = kincl - kpart;
    #pragma unroll
    for (int j=0;j<8;j++){
      if (tt >= acc && tt < acc+kl[j]){ I[36+f] = tid*8+j; I[40+f] = tt-acc; }
      acc += kl[j];
    }
  }
}

// ---- 3: collect candidates + bulk top-k (196 blocks, block-aggregated atomics) ----
__global__ __launch_bounds__(256) void k_collect(const float* dp_, const float* dg_, float* W){
  __shared__ int slds[256];
  __shared__ int base_s, base_c;
  const int bid = blockIdx.x, tid = threadIdx.x;
  const int f = bid / 49;
  const int base = (bid - f*49)*1024;
  int* I = (int*)(W + 24);
  uint32_t* CAND  = (uint32_t*)(W + OFF_RMIN);
  uint32_t* KCAND = CAND + 16384;
  int* SEL = (int*)(W + OFF_SEL);
  const int b1 = I[20+f], b2 = I[28+f], bk = I[36+f];
  float4 d4 = *(const float4*)(dg_ + f*HW + base + tid*4);
  float4 p4 = *(const float4*)(dp_ + f*HW + base + tid*4);
  float dv[4] = {d4.x,d4.y,d4.z,d4.w};
  float pv[4] = {p4.x,p4.y,p4.z,p4.w};
  bool sf[4], cf[4];
  uint32_t cu[4];
  int cnt_s = 0, cnt_c = 0;
  #pragma unroll
  for (int k=0;k<4;++k){
    int r = base + tid*4 + k;
    bool mg = (dv[k] > EPSF) && finitef(dv[k]);
    bool m  = mg && finitef(pv[k]) && (pv[k] > EPSF);
    cu[k] = 0u; cf[k] = false;
    if (m){
      cu[k] = __float_as_uint(pv[k] / fmaxf(dv[k], EPSF));
      int bu = (int)(cu[k]>>18);
      cf[k] = (bu == b1 || bu == b2);
    }
    uint32_t key = ((uint32_t)(mg?1:0) << 20) | (((uint32_t)r*2654435761u) & 0xFFFFFu);
    int kb = (int)(key>>10);
    sf[k] = kb > bk;
    cnt_s += sf[k] ? 1 : 0;
    cnt_c += cf[k] ? 1 : 0;
    if (kb == bk){
      int p = atomicAdd(&I[16+f], 1);
      if (p < 4096) KCAND[f*4096 + p] = (uint32_t)r;
    }
  }
  int packed = (cnt_c<<11) | cnt_s;
  int incl = block_prefix_incl(packed, slds);
  int excl = incl - packed;
  int excl_s = excl & 0x7FF, excl_c = excl >> 11;
  int tot = slds[255];
  if (tid == 0){
    base_s = atomicAdd(&I[0+f],  tot & 0x7FF);
    base_c = atomicAdd(&I[12+f], tot >> 11);
  }
  __syncthreads();
  int ps = base_s + excl_s, pc = base_c + excl_c;
  #pragma unroll
  for (int k=0;k<4;++k){
    int r = base + tid*4 + k;
    if (sf[k]) SEL[(f<<12) + ps++] = r;
    if (cf[k]){ if (pc < 4096) CAND[f*4096 + pc] = cu[k]; pc++; }
  }
}

// exact value at 0-based rank r among {c in sC[0..nc): (c>>18)==b},
// via 3-level LDS histogram refinement (bits [17:10], [9:2], [1:0]).
__device__ uint32_t refine_rank(const uint32_t* sC, int nc, uint32_t b, int r,
                                int* hist, int* slds){
  const int tid = threadIdx.x;
  __shared__ int ssb, srem;
  hist[tid] = 0; __syncthreads();
  for (int t=tid; t<nc; t+=256){
    uint32_t c = sC[t];
    if ((c>>18) == b) atomicAdd(&hist[(c>>10)&0xFF], 1);
  }
  __syncthreads();
  int part = hist[tid];
  int incl = block_prefix_incl(part, slds);
  if (part > 0 && r >= incl-part && r < incl){ ssb = tid; srem = r-(incl-part); }
  __syncthreads();
  uint32_t pfx = (b<<8) | (uint32_t)ssb;
  int r2 = srem;
  __syncthreads();
  hist[tid] = 0; __syncthreads();
  for (int t=tid; t<nc; t+=256){
    uint32_t c = sC[t];
    if ((c>>10) == pfx) atomicAdd(&hist[(c>>2)&0xFF], 1);
  }
  __syncthreads();
  part = hist[tid];
  incl = block_prefix_incl(part, slds);
  if (part > 0 && r2 >= incl-part && r2 < incl){ ssb = tid; srem = r2-(incl-part); }
  __syncthreads();
  uint32_t pfx2 = (pfx<<8) | (uint32_t)ssb;
  int r3 = srem;
  __syncthreads();
  if (tid < 4) hist[tid] = 0;
  __syncthreads();
  for (int t=tid; t<nc; t+=256){
    uint32_t c = sC[t];
    if ((c>>2) == pfx2) atomicAdd(&hist[c&3], 1);
  }
  __syncthreads();
  int h0=hist[0], h1=hist[1], h2=hist[2];
  uint32_t lo = (r3 < h0) ? 0u : (r3 < h0+h1) ? 1u : (r3 < h0+h1+h2) ? 2u : 3u;
  __syncthreads();
  return (pfx2<<2) | lo;
}

// ---- 4: exact median + key-threshold completion, RMIN init, gather (4 blocks) ----
__global__ __launch_bounds__(256) void k_finish(const float* dg_, const float* pts_,
                                                const float* intr, float* W){
  const int f = blockIdx.x, tid = threadIdx.x;
  __shared__ __align__(16) uint32_t smem[8192];   // sC 16KB + sK 16KB
  __shared__ int hist[256];
  __shared__ int slds[256];
  int* I = (int*)(W + 24);
  uint32_t* CAND  = (uint32_t*)(W + OFF_RMIN);
  uint32_t* KCAND = CAND + 16384;
  int* SEL = (int*)(W + OFF_SEL);
  uint32_t* sC = smem;
  uint32_t* sK = smem + 4096;
  int nc = min(I[12+f], 4096), nk = min(I[16+f], 4096);
  for (int t=tid; t<nc; t+=256) sC[t] = CAND[f*4096 + t];
  for (int t=tid; t<nk; t+=256) sK[t] = KCAND[f*4096 + t];
  __syncthreads();
  for (int t=tid; t<4096; t+=256){
    CAND [f*4096 + t] = 0xFF800000u;   // RMIN dir0 slice f = ordenc(+inf)
    KCAND[f*4096 + t] = 0xFF800000u;   // RMIN dir1 slice f
  }
  int nn = I[4+f], mc = I[8+f];
  float scale = 1.f;
  if (nn > 0){
    uint32_t v1 = refine_rank(sC, nc, (uint32_t)I[20+f], I[24+f], hist, slds);
    uint32_t v2 = refine_rank(sC, nc, (uint32_t)I[28+f], I[32+f], hist, slds);
    float med = 0.5f*(__uint_as_float(v1) + __uint_as_float(v2));
    scale = (nn < 16 || !finitef(med)) ? 1.f : fminf(fmaxf(med, 1e-3f), 1e3f);
  }
  {
    int bk = I[36+f], rk = I[40+f];
    uint32_t maskbit = ((uint32_t)bk >> 10) & 1u;
    for (int t=tid; t<nk; t+=256){
      uint32_t i = sK[t];
      uint32_t key = (maskbit<<20) | ((i*2654435761u) & 0xFFFFFu);
      int rank = 0;
      for (int j=0;j<nk;j++){
        uint32_t key2 = (maskbit<<20) | ((sK[j]*2654435761u) & 0xFFFFFu);
        rank += (key2 < key);
      }
      if (rank >= rk){ int p = atomicAdd(&I[0+f], 1); SEL[(f<<12)+p] = (int)i; }
    }
  }
  __syncthreads();
  if (tid == 0){ W[20+f] = scale; W[16+f] = (float)mc; }
  float fx = fmaxf(intr[f*9+0], EPSF), fy = fmaxf(intr[f*9+4], EPSF);
  float cx = intr[f*9+2], cy = intr[f*9+5];
  const float* R = W + 72 + f*12;
  float wl = 0.f;
  for (int t=tid; t<4096; t+=256){
    int idx = SEL[(f<<12)+t];
    float dgv = dg_[f*HW + idx];
    bool mg = (dgv > EPSF) && finitef(dgv);
    float wv = mg ? 1.f : 0.f;
    wl += wv;
    const float* p = pts_ + (size_t)(f*HW + idx)*3;
    ((float4*)(W + OFF_PS))[(f<<12)+t] = make_float4(p[0], p[1], p[2], wv);
    float d = dgv * scale;
    int y = idx / IMW, x = idx - y*IMW;
    float X = ((float)x - cx)/fx * d;
    float Y = ((float)y - cy)/fy * d;
    float4 gs;
    gs.x = R[0]*X + R[1]*Y + R[2]*d + R[9];
    gs.y = R[3]*X + R[4]*Y + R[5]*d + R[10];
    gs.z = R[6]*X + R[7]*Y + R[8]*d + R[11];
    gs.w = wv;
    ((float4*)(W + OFF_GS))[(f<<12)+t] = gs;
  }
  float ws = wsum_f(wl);
  if ((tid & 63) == 0) atomicAdd(&W[12+f], ws);
}

// ---- 5: chamfer row-min (512 blocks, 4 rows/thread, 256-pt tile) + fused normals/depth ----
__global__ __launch_bounds__(256) void k_cham(const float* dp_, const float* dg_,
                                              const float* intr, float* W){
  __shared__ __align__(16) float4 tile[256];   // 4 KB
  __shared__ float rsum[8];
  const int bid = blockIdx.x, tid = threadIdx.x;
  {
    int dir = bid >> 8;
    int rem = bid & 255;
    int f = rem >> 6;
    int t64 = rem & 63;
    int rc = t64 & 3;        // 4 row-chunks of 1024
    int gc = t64 >> 2;       // 16 gt-chunks of 256
    const float4* PS = (const float4*)(W + OFF_PS);
    const float4* GS = (const float4*)(W + OFF_GS);
    const float4* A = dir ? GS : PS;
    const float4* B = dir ? PS : GS;
    uint32_t* RM = (uint32_t*)(W + OFF_RMIN) + dir*16384 + (f<<12);
    {
      float4 b = B[(f<<12) + (gc<<8) + tid];
      float gg = fmaf(b.x,b.x, fmaf(b.y,b.y, b.z*b.z));
      bool v = b.w > 0.f;
      tile[tid] = make_float4(v?b.x:0.f, v?b.y:0.f, v?b.z:0.f, v ? -0.5f*gg : -INFINITY);
    }
    __syncthreads();
    int r0 = (rc<<10) + tid;   // rows r0, r0+256, r0+512, r0+768
    float4 a0 = A[(f<<12)+r0];
    float4 a1 = A[(f<<12)+r0+256];
    float4 a2 = A[(f<<12)+r0+512];
    float4 a3 = A[(f<<12)+r0+768];
    float rh0 = -0.5f*fmaf(a0.x,a0.x,fmaf(a0.y,a0.y,a0.z*a0.z));
    float rh1 = -0.5f*fmaf(a1.x,a1.x,fmaf(a1.y,a1.y,a1.z*a1.z));
    float rh2 = -0.5f*fmaf(a2.x,a2.x,fmaf(a2.y,a2.y,a2.z*a2.z));
    float rh3 = -0.5f*fmaf(a3.x,a3.x,fmaf(a3.y,a3.y,a3.z*a3.z));
    float m0 = -INFINITY, m1 = -INFINITY, m2 = -INFINITY, m3 = -INFINITY;
    #pragma unroll 8
    for (int j=0;j<256;++j){
      float4 g = tile[j];
      float d0 = fmaf(a0.z,g.z, fmaf(a0.y,g.y, fmaf(a0.x,g.x, rh0)));
      float d1 = fmaf(a1.z,g.z, fmaf(a1.y,g.y, fmaf(a1.x,g.x, rh1)));
      float d2 = fmaf(a2.z,g.z, fmaf(a2.y,g.y, fmaf(a2.x,g.x, rh2)));
      float d3 = fmaf(a3.z,g.z, fmaf(a3.y,g.y, fmaf(a3.x,g.x, rh3)));
      m0 = fmaxf(m0, d0 + g.w);
      m1 = fmaxf(m1, d1 + g.w);
      m2 = fmaxf(m2, d2 + g.w);
      m3 = fmaxf(m3, d3 + g.w);
    }
    atomicMin(&RM[r0    ], ordenc(-2.f*m0));
    atomicMin(&RM[r0+256], ordenc(-2.f*m1));
    atomicMin(&RM[r0+512], ordenc(-2.f*m2));
    atomicMin(&RM[r0+768], ordenc(-2.f*m3));
  }
  // fused normals + depth L1 (512 blocks * 392 px = 200704)
  {
    int f = bid >> 7;
    int base = (bid & 127) * 392;
    float sc = W[20+f];
    float fx = fmaxf(intr[f*9+0], EPSF), fy = fmaxf(intr[f*9+4], EPSF);
    float cx = intr[f*9+2], cy = intr[f*9+5];
    float dl = 0.f, nl = 0.f;
    #pragma unroll
    for (int it=0; it<2; ++it){
      int t = tid + it*256;
      if (t < 392){
        int r = base + t;
        int y = r / IMW, x = r - y*IMW;
        float dgv = dg_[f*HW+r], dpv = dp_[f*HW+r];
        bool mg = (dgv > EPSF) && finitef(dgv);
        float mv = mg ? 1.f : 0.f;
        dl += fabsf(dpv - dgv*sc) * mv;
        if (x > 0 && x < IMW-1 && y > 0 && y < IMW-1){
          float3 n1 = normal_at(dp_ + f*HW, 1.f, x, y, cx, cy, fx, fy);
          float3 n2 = normal_at(dg_ + f*HW, sc,  x, y, cx, cy, fx, fy);
          float l1 = sqrtf(n1.x*n1.x + n1.y*n1.y + n1.z*n1.z);
          float l2 = sqrtf(n2.x*n2.x + n2.y*n2.y + n2.z*n2.z);
          float i1 = 1.f/fmaxf(l1, EPSF), i2 = 1.f/fmaxf(l2, EPSF);
          float cosv = (n1.x*n2.x + n1.y*n2.y + n1.z*n2.z)*i1*i2;
          cosv = fminf(fmaxf(cosv, -1.f), 1.f);
          nl += (1.f - cosv) * mv;
        } else {
          nl += mv;   // border: both normals zero -> cos=0
        }
      }
    }
    float ds = wsum_f(dl), ns2 = wsum_f(nl);
    if ((tid & 63) == 0){ rsum[tid>>6] = ds; rsum[4+(tid>>6)] = ns2; }
    __syncthreads();
    if (tid == 0){
      atomicAdd(&W[1], rsum[0]+rsum[1]+rsum[2]+rsum[3]);
      atomicAdd(&W[3], rsum[4]+rsum[5]+rsum[6]+rsum[7]);
    }
  }
}

// ---- 6: chamfer finish + final combine (1 block, 1024 threads) ----
__global__ __launch_bounds__(1024) void k_final(float* W, float* out){
  __shared__ float flds[16];
  const int tid = threadIdx.x;
  const uint32_t* RM = (const uint32_t*)(W + OFF_RMIN);
  float sums[8];
  #pragma unroll
  for (int grp=0; grp<8; ++grp){
    int dir = grp >> 2, f = grp & 3;
    const float4* A = dir ? (const float4*)(W + OFF_GS) : (const float4*)(W + OFF_PS);
    float local = 0.f;
    for (int row=tid; row<4096; row+=1024){
      float val = orddec(RM[dir*16384 + (f<<12) + row]);
      float d = isinf(val) ? 1e9f : sqrtf(fmaxf(val, 1e-12f));
      local += d * A[(f<<12)+row].w;
    }
    local = wsum_f(local);
    __syncthreads();
    if ((tid & 63) == 0) flds[tid>>6] = local;
    __syncthreads();
    float s = 0.f;
    if (tid == 0){ for (int k=0;k<16;k++) s += flds[k]; }
    sums[grp] = s;    // valid on thread 0
    __syncthreads();
  }
  if (tid == 0){
    float md = fmaxf(W[16]+W[17]+W[18]+W[19], 1.f);
    float depth_loss  = W[1]/md;
    float normal_loss = W[3]/md;
    float cds = 0.f, oks = 0.f;
    for (int f=0; f<4; f++){
      if (W[16+f] >= 10.f){
        float denom = fmaxf(W[12+f], 1.f);
        cds += sums[f]/denom + sums[4+f]/denom;
        oks += 1.f;
      }
    }
    float points_loss = cds / fmaxf(oks, 1.f);
    out[0] = W[0] + depth_loss + points_loss + normal_loss;
  }
}

extern "C" void kernel_launch(void* const* d_in, const int* in_sizes, int n_in,
                              void* d_out, int out_size, void* d_ws, size_t ws_size,
                              hipStream_t stream){
  const float* depth_pred  = (const float*)d_in[0];
  const float* points_pred = (const float*)d_in[1];
  const float* depth_gt    = (const float*)d_in[2];
  const float* intr        = (const float*)d_in[3];
  const float* pose_pred   = (const float*)d_in[4];
  const float* pose_gt     = (const float*)d_in[5];
  float* out = (float*)d_out;
  float* W   = (float*)d_ws;

  k_zero   <<<73,  256,  0, stream>>>(W);
  k_hist   <<<33,  1024, 0, stream>>>(depth_pred, depth_gt, pose_pred, pose_gt, W);
  k_scan   <<<4,   256,  0, stream>>>(W);
  k_collect<<<196, 256,  0, stream>>>(depth_pred, depth_gt, W);
  k_finish <<<4,   256,  0, stream>>>(depth_gt, points_pred, intr, W);
  k_cham   <<<512, 256,  0, stream>>>(depth_pred, depth_gt, intr, W);
  k_final  <<<1,   1024, 0, stream>>>(W, out);
}